// Round 4
// baseline (151.931 us; speedup 1.0000x reference)
//
#include <hip/hip_runtime.h>
#include <hip/hip_bf16.h>

typedef __attribute__((ext_vector_type(4)))  float f32x4;
typedef __attribute__((ext_vector_type(16))) float f32x16;
typedef __attribute__((ext_vector_type(8)))  short short8;
typedef __attribute__((ext_vector_type(4)))  short short4v;

__device__ __forceinline__ short f2bf(float f) {
  union { float f; unsigned u; } x; x.f = f;
  unsigned r = (x.u + 0x7FFFu + ((x.u >> 16) & 1u)) >> 16;
  return (short)r;
}
__device__ __forceinline__ float bf2f(short s) {
  union { unsigned u; float f; } x; x.u = ((unsigned)(unsigned short)s) << 16;
  return x.f;
}
__device__ __forceinline__ unsigned pk2(float lo, float hi) {
  return (unsigned)(unsigned short)f2bf(lo) | ((unsigned)(unsigned short)f2bf(hi) << 16);
}

// ---------------- cast f32 -> bf16, vectorized x4 ----------------
__global__ __launch_bounds__(256) void k_cast(const float* __restrict__ in,
                                              short* __restrict__ out, int n4) {
  int i = blockIdx.x * 256 + threadIdx.x;
  if (i >= n4) return;
  f32x4 v = ((const f32x4*)in)[i];
  short4v s;
  s[0] = f2bf(v[0]); s[1] = f2bf(v[1]); s[2] = f2bf(v[2]); s[3] = f2bf(v[3]);
  ((short4v*)out)[i] = s;
}

// ---------------- pack w_q/w_k/w_v -> WqkvT bf16 [3072][1024] ----------------
__global__ __launch_bounds__(256) void k_pack(const float* __restrict__ wq,
                                              const float* __restrict__ wk,
                                              const float* __restrict__ wv,
                                              short* __restrict__ WT) {
  int nt = blockIdx.x, et = blockIdx.y, sel = blockIdx.z;
  const float* w = sel == 0 ? wq : (sel == 1 ? wk : wv);
  __shared__ float tile[64][65];
  int tid = threadIdx.x;
  int cl = tid & 63, rw = tid >> 6;
#pragma unroll
  for (int j = 0; j < 16; ++j) {
    int el = j * 4 + rw;
    tile[el][cl] = w[(size_t)(et * 64 + el) * 1024 + nt * 64 + cl];
  }
  __syncthreads();
#pragma unroll
  for (int j = 0; j < 16; ++j) {
    int nl = j * 4 + rw;
    int n = sel * 1024 + nt * 64 + nl;
    WT[(size_t)n * 1024 + et * 64 + cl] = f2bf(tile[cl][nl]);
  }
}

// ---------------- GEMM C[M][N] = A[M][K] * B^T[N][K], bf16 in, f32 acc ----------------
// EPI==0: scatter Q(*0.125*log2e)/K -> [BH][2048][64], V -> V^T [BH][64][2048]; EPI==1: f32 out
template <int EPI>
__global__ __launch_bounds__(256) void k_gemm(const short* __restrict__ A,
                                              const short* __restrict__ B,
                                              short* __restrict__ Qo, short* __restrict__ Ko,
                                              short* __restrict__ Vo, float* __restrict__ out,
                                              int M, int N, int K) {
  __shared__ short As[128][40];
  __shared__ short Bs[128][40];
  int tid = threadIdx.x;
  int bm = blockIdx.y * 128, bn = blockIdx.x * 128;
  int wid = tid >> 6, lane = tid & 63;
  int wm = (wid >> 1) * 64, wn = (wid & 1) * 64;
  int lg = lane >> 4, lr = lane & 15;
  f32x4 acc[4][4] = {};

  int sr = tid >> 2, sc = tid & 3;
  const short* Ar0 = A + (size_t)(bm + sr) * K;
  const short* Ar1 = A + (size_t)(bm + sr + 64) * K;
  const short* Br0 = B + (size_t)(bn + sr) * K;
  const short* Br1 = B + (size_t)(bn + sr + 64) * K;

  short8 pa0 = *(const short8*)&Ar0[sc * 8];
  short8 pa1 = *(const short8*)&Ar1[sc * 8];
  short8 pb0 = *(const short8*)&Br0[sc * 8];
  short8 pb1 = *(const short8*)&Br1[sc * 8];

  int nk = K >> 5;
  for (int kt = 0; kt < nk; ++kt) {
    __syncthreads();
    *(short8*)&As[sr][sc * 8] = pa0;
    *(short8*)&As[sr + 64][sc * 8] = pa1;
    *(short8*)&Bs[sr][sc * 8] = pb0;
    *(short8*)&Bs[sr + 64][sc * 8] = pb1;
    if (kt + 1 < nk) {
      int ko = (kt + 1) * 32;
      pa0 = *(const short8*)&Ar0[ko + sc * 8];
      pa1 = *(const short8*)&Ar1[ko + sc * 8];
      pb0 = *(const short8*)&Br0[ko + sc * 8];
      pb1 = *(const short8*)&Br1[ko + sc * 8];
    }
    __syncthreads();
    short8 af[4], bf_[4];
#pragma unroll
    for (int mt = 0; mt < 4; ++mt)
      af[mt] = *(const short8*)&As[wm + mt * 16 + lr][lg * 8];
#pragma unroll
    for (int ntl = 0; ntl < 4; ++ntl)
      bf_[ntl] = *(const short8*)&Bs[wn + ntl * 16 + lr][lg * 8];
#pragma unroll
    for (int mt = 0; mt < 4; ++mt)
#pragma unroll
      for (int ntl = 0; ntl < 4; ++ntl)
        acc[mt][ntl] = __builtin_amdgcn_mfma_f32_16x16x32_bf16(af[mt], bf_[ntl], acc[mt][ntl], 0, 0, 0);
  }

#pragma unroll
  for (int mt = 0; mt < 4; ++mt)
#pragma unroll
    for (int ntl = 0; ntl < 4; ++ntl)
#pragma unroll
      for (int rr = 0; rr < 4; ++rr) {
        int m = bm + wm + mt * 16 + lg * 4 + rr;
        int n = bn + wn + ntl * 16 + lr;
        float val = acc[mt][ntl][rr];
        if (EPI == 0) {
          int b = m >> 11, s = m & 2047;
          int sel = n >> 10, hk = n & 1023;
          int h = hk >> 6, kd = hk & 63;
          // 0.125 * log2(e): logits move to log2 domain -> exp2 in softmax
          if (sel == 0) Qo[((size_t)(b * 16 + h) * 2048 + s) * 64 + kd] = f2bf(val * 0.18033688011112042f);
          else if (sel == 1) Ko[((size_t)(b * 16 + h) * 2048 + s) * 64 + kd] = f2bf(val);
          else Vo[((size_t)(b * 16 + h) * 64 + kd) * 2048 + s] = f2bf(val);  // V^T
        } else {
          out[(size_t)m * 1024 + n] = val;
        }
      }
}

// ---------------- causal flash attention: swapped 32x32x16, LDS-free, 2-way kv-split --------
// Q,K: [32][2048][64] bf16 (Q pre-scaled 1/8*log2e). VT: [32][64][2048].
// Partials: P0/P1 [32][2048][64] bf16 (unnormalized O), ML [32*2048][4] f32 {m0,l0,m1,l1}.
// Block a: all 4 waves process exactly c tiles; per-CU c-sets sum to 66.
__global__ __launch_bounds__(256, 4) void k_attn(const short* __restrict__ Q,
                                                 const short* __restrict__ K,
                                                 const short* __restrict__ VT,
                                                 short* __restrict__ P0,
                                                 short* __restrict__ P1,
                                                 float* __restrict__ ML) {
  const int S = 2048;
  int bh = blockIdx.x, a = blockIdx.y;
  int kk = a >> 3, a0 = a & 7;
  int c = (kk == 0) ? (a0 + 1) : (kk == 1) ? (16 - a0) : (kk == 2) ? (17 + a0) : (32 - a0);
  int wid = threadIdx.x >> 6, lane = threadIdx.x & 63;
  int qw, half;
  if (wid == 0)      { qw = 2 * c - 2;       half = 0; }
  else if (wid == 1) { qw = 2 * c - 1;       half = 0; }
  else if (wid == 2) { qw = 2 * c - 1;       half = 1; }
  else               { qw = (2 * c) & 63;    half = 1; }
  int nt_total = qw + 1;
  int nt0 = (nt_total + 1) >> 1;
  int tb = half ? nt0 : 0;
  int te = half ? nt_total : nt0;

  int hi = lane >> 5, ln = lane & 31;
  int q_g = qw * 32 + ln;

  const short* Qb = Q + (size_t)bh * S * 64;
  const short* Kb = K + (size_t)bh * S * 64;
  const short* Vb = VT + (size_t)bh * 64 * S;

  // Q fragments: B[k=d][col=q]
  short8 qf[4];
#pragma unroll
  for (int ds = 0; ds < 4; ++ds)
    qf[ds] = *(const short8*)&Qb[(size_t)q_g * 64 + ds * 16 + hi * 8];

  f32x16 acoA = {}, acoB = {};
  float m = -1e30f, l = 0.f;

  if (tb < te) {
    short8 kc[4], kn[4];
#pragma unroll
    for (int ds = 0; ds < 4; ++ds)
      kc[ds] = *(const short8*)&Kb[(size_t)(tb * 32 + ln) * 64 + ds * 16 + hi * 8];

    for (int t = tb; t < te; ++t) {
      const size_t vro = (size_t)ln * S + t * 32 + hi * 8;
      short8 v00 = *(const short8*)&Vb[vro];
      short8 v01 = *(const short8*)&Vb[vro + 16];
      short8 v10 = *(const short8*)&Vb[vro + (size_t)32 * S];
      short8 v11 = *(const short8*)&Vb[vro + (size_t)32 * S + 16];
      if (t + 1 < te) {
#pragma unroll
        for (int ds = 0; ds < 4; ++ds)
          kn[ds] = *(const short8*)&Kb[(size_t)((t + 1) * 32 + ln) * 64 + ds * 16 + hi * 8];
      }

      // S[kv][q] = K Q^T (log2 domain): lane holds 16 kv values for its own q
      f32x16 sa = {};
#pragma unroll
      for (int ds = 0; ds < 4; ++ds)
        sa = __builtin_amdgcn_mfma_f32_32x32x16_bf16(kc[ds], qf[ds], sa, 0, 0, 0);

      if (t == qw) {  // diagonal tile: causal mask
#pragma unroll
        for (int r = 0; r < 16; ++r) {
          int kv_g = t * 32 + (r & 3) + 8 * (r >> 2) + 4 * hi;
          if (kv_g > q_g) sa[r] = -1e30f;
        }
      }

      // row max: in-register tree + ONE cross-lane shfl
      float x0 = fmaxf(sa[0], sa[1]),  x1 = fmaxf(sa[2], sa[3]);
      float x2 = fmaxf(sa[4], sa[5]),  x3 = fmaxf(sa[6], sa[7]);
      float x4 = fmaxf(sa[8], sa[9]),  x5 = fmaxf(sa[10], sa[11]);
      float x6 = fmaxf(sa[12], sa[13]), x7 = fmaxf(sa[14], sa[15]);
      x0 = fmaxf(x0, x1); x2 = fmaxf(x2, x3); x4 = fmaxf(x4, x5); x6 = fmaxf(x6, x7);
      x0 = fmaxf(x0, x2); x4 = fmaxf(x4, x6);
      float mx = fmaxf(x0, x4);
      mx = fmaxf(mx, __shfl_xor(mx, 32));

      float mnew = fmaxf(m, mx);
      float alpha = exp2f(m - mnew);
      m = mnew;

      float p[16];
#pragma unroll
      for (int r = 0; r < 16; ++r) p[r] = exp2f(sa[r] - mnew);
      float s0 = (p[0] + p[1]) + (p[2] + p[3]);
      float s1 = (p[4] + p[5]) + (p[6] + p[7]);
      float s2 = (p[8] + p[9]) + (p[10] + p[11]);
      float s3 = (p[12] + p[13]) + (p[14] + p[15]);
      float rsum = (s0 + s1) + (s2 + s3);
      rsum += __shfl_xor(rsum, 32);
      l = l * alpha + rsum;
      acoA *= alpha;
      acoB *= alpha;

      // assemble P^T fragments (B[k=kv][col=q]) via pack + lane^32 exchange
#pragma unroll
      for (int s = 0; s < 2; ++s) {
        unsigned c0 = pk2(p[8 * s + 0], p[8 * s + 1]);
        unsigned c1 = pk2(p[8 * s + 2], p[8 * s + 3]);
        unsigned c2 = pk2(p[8 * s + 4], p[8 * s + 5]);
        unsigned c3 = pk2(p[8 * s + 6], p[8 * s + 7]);
        unsigned pc0 = (unsigned)__shfl_xor((int)c0, 32);
        unsigned pc1 = (unsigned)__shfl_xor((int)c1, 32);
        unsigned pc2 = (unsigned)__shfl_xor((int)c2, 32);
        unsigned pc3 = (unsigned)__shfl_xor((int)c3, 32);
        union { unsigned u[4]; short8 v; } pb;
        pb.u[0] = hi ? pc2 : c0;
        pb.u[1] = hi ? pc3 : c1;
        pb.u[2] = hi ? c2 : pc0;
        pb.u[3] = hi ? c3 : pc1;
        if (s == 0) {
          acoA = __builtin_amdgcn_mfma_f32_32x32x16_bf16(v00, pb.v, acoA, 0, 0, 0);
          acoB = __builtin_amdgcn_mfma_f32_32x32x16_bf16(v10, pb.v, acoB, 0, 0, 0);
        } else {
          acoA = __builtin_amdgcn_mfma_f32_32x32x16_bf16(v01, pb.v, acoA, 0, 0, 0);
          acoB = __builtin_amdgcn_mfma_f32_32x32x16_bf16(v11, pb.v, acoB, 0, 0, 0);
        }
      }
#pragma unroll
      for (int ds = 0; ds < 4; ++ds) kc[ds] = kn[ds];
    }
  }

  // write partial: unnormalized O (bf16) + (m, l)
  int row = (bh << 11) + q_g;
  ML[row * 4 + half * 2 + 0] = m;
  ML[row * 4 + half * 2 + 1] = l;
  short* Op = half ? P1 : P0;
  size_t base = (size_t)row * 64;
#pragma unroll
  for (int g = 0; g < 4; ++g) {
    int d0 = 8 * g + 4 * hi;
    *(unsigned*)&Op[base + d0]          = pk2(acoA[4 * g], acoA[4 * g + 1]);
    *(unsigned*)&Op[base + d0 + 2]      = pk2(acoA[4 * g + 2], acoA[4 * g + 3]);
    *(unsigned*)&Op[base + 32 + d0]     = pk2(acoB[4 * g], acoB[4 * g + 1]);
    *(unsigned*)&Op[base + 32 + d0 + 2] = pk2(acoB[4 * g + 2], acoB[4 * g + 3]);
  }
}

// ---------------- merge the two kv-halves -> Ob [2][2048][1024] bf16 ----------------
__global__ __launch_bounds__(256) void k_merge(const short* __restrict__ P0,
                                               const short* __restrict__ P1,
                                               const float* __restrict__ ML,
                                               short* __restrict__ O) {
  int gi = blockIdx.x * 256 + threadIdx.x;  // 262144
  int row = gi >> 2;                        // bh*2048 + q
  int dc = (gi & 3) << 4;
  float m0 = ML[row * 4 + 0], l0 = ML[row * 4 + 1];
  float m1 = ML[row * 4 + 2], l1 = ML[row * 4 + 3];
  float M = fmaxf(m0, m1);
  float w0 = exp2f(m0 - M), w1 = exp2f(m1 - M);
  float rL = 1.f / (l0 * w0 + l1 * w1);
  w0 *= rL; w1 *= rL;
  size_t pbase = (size_t)row * 64 + dc;
  short8 a0 = *(const short8*)&P0[pbase];
  short8 a1 = *(const short8*)&P0[pbase + 8];
  short8 b0 = *(const short8*)&P1[pbase];
  short8 b1 = *(const short8*)&P1[pbase + 8];
  int bh = row >> 11, q = row & 2047;
  int b = bh >> 4, h = bh & 15;
  size_t obase = ((size_t)b * 2048 + q) * 1024 + h * 64 + dc;
  short8 o0, o1;
#pragma unroll
  for (int j = 0; j < 8; ++j) {
    o0[j] = f2bf(bf2f(a0[j]) * w0 + bf2f(b0[j]) * w1);
    o1[j] = f2bf(bf2f(a1[j]) * w0 + bf2f(b1[j]) * w1);
  }
  *(short8*)&O[obase] = o0;
  *(short8*)&O[obase + 8] = o1;
}

extern "C" void kernel_launch(void* const* d_in, const int* in_sizes, int n_in,
                              void* d_out, int out_size, void* d_ws, size_t ws_size,
                              hipStream_t stream) {
  const float* x  = (const float*)d_in[0];
  const float* wq = (const float*)d_in[1];
  const float* wk = (const float*)d_in[2];
  const float* wv = (const float*)d_in[3];
  const float* wo = (const float*)d_in[4];
  float* out = (float*)d_out;
  char* ws = (char*)d_ws;

  short* x_bf  = (short*)(ws);                       // 8 MB (dead after gemm0)
  short* WqkvT = (short*)(ws + ((size_t)8 << 20));   // 6 MB (dead after gemm0)
  short* wo_bf = (short*)(ws + ((size_t)14 << 20));  // 2 MB
  short* Qb    = (short*)(ws + ((size_t)16 << 20));  // 8 MB
  short* Kb    = (short*)(ws + ((size_t)24 << 20));  // 8 MB
  short* Vt    = (short*)(ws + ((size_t)32 << 20));  // 8 MB (V^T)
  short* Ob    = (short*)(ws + ((size_t)40 << 20));  // 8 MB
  short* P0    = (short*)(ws);                       // 8 MB, overlays x_bf
  float* ML    = (float*)(ws + ((size_t)8 << 20));   // 1 MB, overlays WqkvT
  short* P1    = (short*)(ws + ((size_t)48 << 20));  // 8 MB

  k_cast<<<4096, 256, 0, stream>>>(x, x_bf, 1048576);
  k_cast<<<1024, 256, 0, stream>>>(wo, wo_bf, 262144);
  k_pack<<<dim3(16, 16, 3), 256, 0, stream>>>(wq, wk, wv, WqkvT);
  k_gemm<0><<<dim3(24, 32), 256, 0, stream>>>(x_bf, WqkvT, Qb, Kb, Vt, nullptr, 4096, 3072, 1024);
  k_attn<<<dim3(32, 32), 256, 0, stream>>>(Qb, Kb, Vt, P0, P1, ML);
  k_merge<<<1024, 256, 0, stream>>>(P0, P1, ML, Ob);
  k_gemm<1><<<dim3(8, 32), 256, 0, stream>>>(Ob, wo_bf, nullptr, nullptr, nullptr, out, 4096, 1024, 1024);
}

// Round 5
// 145.592 us; speedup vs baseline: 1.0435x; 1.0435x over previous
//
#include <hip/hip_runtime.h>
#include <hip/hip_bf16.h>

typedef __attribute__((ext_vector_type(4)))  float f32x4;
typedef __attribute__((ext_vector_type(16))) float f32x16;
typedef __attribute__((ext_vector_type(8)))  short short8;
typedef __attribute__((ext_vector_type(4)))  short short4v;

__device__ __forceinline__ short f2bf(float f) {
  union { float f; unsigned u; } x; x.f = f;
  unsigned r = (x.u + 0x7FFFu + ((x.u >> 16) & 1u)) >> 16;
  return (short)r;
}
__device__ __forceinline__ unsigned cvtpk(float lo, float hi) {
  unsigned r;
  asm("v_cvt_pk_bf16_f32 %0, %1, %2" : "=v"(r) : "v"(lo), "v"(hi));
  return r;
}

// ---------------- cast f32 -> bf16, vectorized x4 ----------------
__global__ __launch_bounds__(256) void k_cast(const float* __restrict__ in,
                                              short* __restrict__ out, int n4) {
  int i = blockIdx.x * 256 + threadIdx.x;
  if (i >= n4) return;
  f32x4 v = ((const f32x4*)in)[i];
  short4v s;
  s[0] = f2bf(v[0]); s[1] = f2bf(v[1]); s[2] = f2bf(v[2]); s[3] = f2bf(v[3]);
  ((short4v*)out)[i] = s;
}

// ---------------- pack w_q/w_k/w_v -> WqkvT bf16 [3072][1024] ----------------
__global__ __launch_bounds__(256) void k_pack(const float* __restrict__ wq,
                                              const float* __restrict__ wk,
                                              const float* __restrict__ wv,
                                              short* __restrict__ WT) {
  int nt = blockIdx.x, et = blockIdx.y, sel = blockIdx.z;
  const float* w = sel == 0 ? wq : (sel == 1 ? wk : wv);
  __shared__ float tile[64][65];
  int tid = threadIdx.x;
  int cl = tid & 63, rw = tid >> 6;
#pragma unroll
  for (int j = 0; j < 16; ++j) {
    int el = j * 4 + rw;
    tile[el][cl] = w[(size_t)(et * 64 + el) * 1024 + nt * 64 + cl];
  }
  __syncthreads();
#pragma unroll
  for (int j = 0; j < 16; ++j) {
    int nl = j * 4 + rw;
    int n = sel * 1024 + nt * 64 + nl;
    WT[(size_t)n * 1024 + et * 64 + cl] = f2bf(tile[cl][nl]);
  }
}

// ---------------- GEMM C[M][N] = A[M][K] * B^T[N][K], bf16 in, f32 acc ----------------
// EPI==0: scatter Q(*0.125*log2e)/K -> [BH][2048][64], V -> V^T [BH][64][2048]; EPI==1: f32 out
template <int EPI>
__global__ __launch_bounds__(256) void k_gemm(const short* __restrict__ A,
                                              const short* __restrict__ B,
                                              short* __restrict__ Qo, short* __restrict__ Ko,
                                              short* __restrict__ Vo, float* __restrict__ out,
                                              int M, int N, int K) {
  __shared__ short As[128][40];
  __shared__ short Bs[128][40];
  int tid = threadIdx.x;
  int bm = blockIdx.y * 128, bn = blockIdx.x * 128;
  int wid = tid >> 6, lane = tid & 63;
  int wm = (wid >> 1) * 64, wn = (wid & 1) * 64;
  int lg = lane >> 4, lr = lane & 15;
  f32x4 acc[4][4] = {};

  int sr = tid >> 2, sc = tid & 3;
  const short* Ar0 = A + (size_t)(bm + sr) * K;
  const short* Ar1 = A + (size_t)(bm + sr + 64) * K;
  const short* Br0 = B + (size_t)(bn + sr) * K;
  const short* Br1 = B + (size_t)(bn + sr + 64) * K;

  short8 pa0 = *(const short8*)&Ar0[sc * 8];
  short8 pa1 = *(const short8*)&Ar1[sc * 8];
  short8 pb0 = *(const short8*)&Br0[sc * 8];
  short8 pb1 = *(const short8*)&Br1[sc * 8];

  int nk = K >> 5;
  for (int kt = 0; kt < nk; ++kt) {
    __syncthreads();
    *(short8*)&As[sr][sc * 8] = pa0;
    *(short8*)&As[sr + 64][sc * 8] = pa1;
    *(short8*)&Bs[sr][sc * 8] = pb0;
    *(short8*)&Bs[sr + 64][sc * 8] = pb1;
    if (kt + 1 < nk) {
      int ko = (kt + 1) * 32;
      pa0 = *(const short8*)&Ar0[ko + sc * 8];
      pa1 = *(const short8*)&Ar1[ko + sc * 8];
      pb0 = *(const short8*)&Br0[ko + sc * 8];
      pb1 = *(const short8*)&Br1[ko + sc * 8];
    }
    __syncthreads();
    short8 af[4], bf_[4];
#pragma unroll
    for (int mt = 0; mt < 4; ++mt)
      af[mt] = *(const short8*)&As[wm + mt * 16 + lr][lg * 8];
#pragma unroll
    for (int ntl = 0; ntl < 4; ++ntl)
      bf_[ntl] = *(const short8*)&Bs[wn + ntl * 16 + lr][lg * 8];
#pragma unroll
    for (int mt = 0; mt < 4; ++mt)
#pragma unroll
      for (int ntl = 0; ntl < 4; ++ntl)
        acc[mt][ntl] = __builtin_amdgcn_mfma_f32_16x16x32_bf16(af[mt], bf_[ntl], acc[mt][ntl], 0, 0, 0);
  }

#pragma unroll
  for (int mt = 0; mt < 4; ++mt)
#pragma unroll
    for (int ntl = 0; ntl < 4; ++ntl)
#pragma unroll
      for (int rr = 0; rr < 4; ++rr) {
        int m = bm + wm + mt * 16 + lg * 4 + rr;
        int n = bn + wn + ntl * 16 + lr;
        float val = acc[mt][ntl][rr];
        if (EPI == 0) {
          int b = m >> 11, s = m & 2047;
          int sel = n >> 10, hk = n & 1023;
          int h = hk >> 6, kd = hk & 63;
          // 0.125 * log2(e): logits in log2 domain -> exp2 in softmax
          if (sel == 0) Qo[((size_t)(b * 16 + h) * 2048 + s) * 64 + kd] = f2bf(val * 0.18033688011112042f);
          else if (sel == 1) Ko[((size_t)(b * 16 + h) * 2048 + s) * 64 + kd] = f2bf(val);
          else Vo[((size_t)(b * 16 + h) * 64 + kd) * 2048 + s] = f2bf(val);  // V^T
        } else {
          out[(size_t)m * 1024 + n] = val;
        }
      }
}

// ---------------- causal flash attention v3: LDS-shared tiles, swapped 32x32x16 ----------------
// Q,K: [32][2048][64] bf16 (Q pre-scaled 1/8*log2e). VT: [32][64][2048]. O: [2][2048][1024] bf16.
// Block = 2 waves (128 thr), wave w -> qw = 2g + w. K/V tile staged once per block, coalesced,
// double-buffered, XOR-swizzled (conflict-free ds_read_b128). One barrier per tile.
__global__ __launch_bounds__(128, 2) void k_attn(const short* __restrict__ Q,
                                                 const short* __restrict__ K,
                                                 const short* __restrict__ VT,
                                                 short* __restrict__ O) {
  const int S = 2048;
  int bh = blockIdx.x;
  int y = blockIdx.y;
  // per-CU balance: co-resident y-set {y0,y0+8,y0+16,y0+24} -> g {y0,15-y0,16+y0,31-y0}
  int y0 = y & 7, sel = y >> 3;
  int g = (sel == 0) ? y0 : (sel == 1) ? (15 - y0) : (sel == 2) ? (16 + y0) : (31 - y0);

  int tid = threadIdx.x;
  int wid = tid >> 6, lane = tid & 63;
  int hi = lane >> 5, ln = lane & 31;
  int qw = 2 * g + wid;
  int ntile = qw + 1;
  int tmax = 2 * g + 2;
  int q_g = qw * 32 + ln;

  __shared__ short Ks[2][32][64];
  __shared__ short Vs[2][64][32];

  const short* Qb = Q + (size_t)bh * S * 64;
  const short* Kb = K + (size_t)bh * S * 64;
  const short* Vb = VT + (size_t)bh * 64 * S;

  // Q fragments: B[k=d][col=q]
  short8 qf[4];
#pragma unroll
  for (int ds = 0; ds < 4; ++ds)
    qf[ds] = *(const short8*)&Qb[(size_t)q_g * 64 + ds * 16 + hi * 8];

  // staging thread mapping
  int kr = tid >> 2, kcb = tid & 3;          // K: row 0..31, chunks kcb, kcb+4
  int vd = tid >> 1, vcb = tid & 1;          // V: row d 0..63, chunks vcb, vcb+2
  const short* kgp = Kb + (size_t)kr * 64;
  const short* vgp = Vb + (size_t)vd * S;

  // prefetch tile 0
  short8 kreg0 = *(const short8*)&kgp[(size_t)0 + kcb * 8];
  short8 kreg1 = *(const short8*)&kgp[(size_t)0 + (kcb + 4) * 8];
  short8 vreg0 = *(const short8*)&vgp[(size_t)0 + vcb * 8];
  short8 vreg1 = *(const short8*)&vgp[(size_t)0 + (vcb + 2) * 8];

  f32x16 acoA = {}, acoB = {};
  float m = -1e30f, l = 0.f;

  for (int t = 0; t < tmax; ++t) {
    int buf = t & 1;
    // stage current tile (swizzled, conflict-free)
    *(short8*)&Ks[buf][kr][(kcb ^ (kr & 7)) * 8]       = kreg0;
    *(short8*)&Ks[buf][kr][((kcb + 4) ^ (kr & 7)) * 8] = kreg1;
    *(short8*)&Vs[buf][vd][(vcb ^ (vd & 3)) * 8]       = vreg0;
    *(short8*)&Vs[buf][vd][((vcb + 2) ^ (vd & 3)) * 8] = vreg1;
    // prefetch next tile (latency hides under compute)
    if (t + 1 < tmax) {
      size_t ko = (size_t)(t + 1) * 32 * 64;
      size_t vo = (size_t)(t + 1) * 32;
      kreg0 = *(const short8*)&kgp[ko + kcb * 8];
      kreg1 = *(const short8*)&kgp[ko + (kcb + 4) * 8];
      vreg0 = *(const short8*)&vgp[vo + vcb * 8];
      vreg1 = *(const short8*)&vgp[vo + (vcb + 2) * 8];
    }
    __syncthreads();

    if (t < ntile) {
      // K fragments from LDS: A[row=kv][k=d]
      short8 kc0 = *(const short8*)&Ks[buf][ln][((0 + hi) ^ (ln & 7)) * 8];
      short8 kc1 = *(const short8*)&Ks[buf][ln][((2 + hi) ^ (ln & 7)) * 8];
      short8 kc2 = *(const short8*)&Ks[buf][ln][((4 + hi) ^ (ln & 7)) * 8];
      short8 kc3 = *(const short8*)&Ks[buf][ln][((6 + hi) ^ (ln & 7)) * 8];
      // S[kv][q] = K Q^T (log2 domain)
      f32x16 sa = {};
      sa = __builtin_amdgcn_mfma_f32_32x32x16_bf16(kc0, qf[0], sa, 0, 0, 0);
      sa = __builtin_amdgcn_mfma_f32_32x32x16_bf16(kc1, qf[1], sa, 0, 0, 0);
      sa = __builtin_amdgcn_mfma_f32_32x32x16_bf16(kc2, qf[2], sa, 0, 0, 0);
      sa = __builtin_amdgcn_mfma_f32_32x32x16_bf16(kc3, qf[3], sa, 0, 0, 0);

      if (t == qw) {  // diagonal tile: causal mask
#pragma unroll
        for (int r = 0; r < 16; ++r) {
          int kv_g = t * 32 + (r & 3) + 8 * (r >> 2) + 4 * hi;
          if (kv_g > q_g) sa[r] = -1e30f;
        }
      }

      // V^T fragments from LDS: A[row=d][k=kv]
      short8 v00 = *(const short8*)&Vs[buf][ln][((0 + hi) ^ (ln & 3)) * 8];
      short8 v01 = *(const short8*)&Vs[buf][ln][((2 + hi) ^ (ln & 3)) * 8];
      short8 v10 = *(const short8*)&Vs[buf][32 + ln][((0 + hi) ^ (ln & 3)) * 8];
      short8 v11 = *(const short8*)&Vs[buf][32 + ln][((2 + hi) ^ (ln & 3)) * 8];

      // row max: in-register tree + one cross-lane shfl
      float x0 = fmaxf(sa[0], sa[1]),  x1 = fmaxf(sa[2], sa[3]);
      float x2 = fmaxf(sa[4], sa[5]),  x3 = fmaxf(sa[6], sa[7]);
      float x4 = fmaxf(sa[8], sa[9]),  x5 = fmaxf(sa[10], sa[11]);
      float x6 = fmaxf(sa[12], sa[13]), x7 = fmaxf(sa[14], sa[15]);
      x0 = fmaxf(x0, x1); x2 = fmaxf(x2, x3); x4 = fmaxf(x4, x5); x6 = fmaxf(x6, x7);
      x0 = fmaxf(x0, x2); x4 = fmaxf(x4, x6);
      float mx = fmaxf(x0, x4);
      mx = fmaxf(mx, __shfl_xor(mx, 32));

      float mnew = fmaxf(m, mx);
      float p[16];
#pragma unroll
      for (int r = 0; r < 16; ++r) p[r] = exp2f(sa[r] - mnew);
      float s0 = (p[0] + p[1]) + (p[2] + p[3]);
      float s1 = (p[4] + p[5]) + (p[6] + p[7]);
      float s2 = (p[8] + p[9]) + (p[10] + p[11]);
      float s3 = (p[12] + p[13]) + (p[14] + p[15]);
      float rsum = (s0 + s1) + (s2 + s3);
      rsum += __shfl_xor(rsum, 32);

      if (__all(mx <= m)) {  // exact skip: alpha == 1
        l += rsum;
      } else {
        float alpha = exp2f(m - mnew);
        m = mnew;
        l = l * alpha + rsum;
        acoA *= alpha;
        acoB *= alpha;
      }

      // assemble P^T fragments (B[k=kv][col=q]) via cvt_pk + lane^32 exchange
#pragma unroll
      for (int s = 0; s < 2; ++s) {
        unsigned c0 = cvtpk(p[8 * s + 0], p[8 * s + 1]);
        unsigned c1 = cvtpk(p[8 * s + 2], p[8 * s + 3]);
        unsigned c2 = cvtpk(p[8 * s + 4], p[8 * s + 5]);
        unsigned c3 = cvtpk(p[8 * s + 6], p[8 * s + 7]);
        unsigned pc0 = (unsigned)__shfl_xor((int)c0, 32);
        unsigned pc1 = (unsigned)__shfl_xor((int)c1, 32);
        unsigned pc2 = (unsigned)__shfl_xor((int)c2, 32);
        unsigned pc3 = (unsigned)__shfl_xor((int)c3, 32);
        union { unsigned u[4]; short8 v; } pb;
        pb.u[0] = hi ? pc2 : c0;
        pb.u[1] = hi ? pc3 : c1;
        pb.u[2] = hi ? c2 : pc0;
        pb.u[3] = hi ? c3 : pc1;
        if (s == 0) {
          acoA = __builtin_amdgcn_mfma_f32_32x32x16_bf16(v00, pb.v, acoA, 0, 0, 0);
          acoB = __builtin_amdgcn_mfma_f32_32x32x16_bf16(v10, pb.v, acoB, 0, 0, 0);
        } else {
          acoA = __builtin_amdgcn_mfma_f32_32x32x16_bf16(v01, pb.v, acoA, 0, 0, 0);
          acoB = __builtin_amdgcn_mfma_f32_32x32x16_bf16(v11, pb.v, acoB, 0, 0, 0);
        }
      }
    }
  }

  // normalized output: O[d][q] acc, lane-local q
  float rl = 1.f / l;
  int b = bh >> 4, h = bh & 15;
  size_t obase = ((size_t)b * 2048 + q_g) * 1024 + h * 64;
#pragma unroll
  for (int g4 = 0; g4 < 4; ++g4) {
    int d0 = 8 * g4 + 4 * hi;
    *(unsigned*)&O[obase + d0]          = cvtpk(acoA[4 * g4] * rl, acoA[4 * g4 + 1] * rl);
    *(unsigned*)&O[obase + d0 + 2]      = cvtpk(acoA[4 * g4 + 2] * rl, acoA[4 * g4 + 3] * rl);
    *(unsigned*)&O[obase + 32 + d0]     = cvtpk(acoB[4 * g4] * rl, acoB[4 * g4 + 1] * rl);
    *(unsigned*)&O[obase + 32 + d0 + 2] = cvtpk(acoB[4 * g4 + 2] * rl, acoB[4 * g4 + 3] * rl);
  }
}

extern "C" void kernel_launch(void* const* d_in, const int* in_sizes, int n_in,
                              void* d_out, int out_size, void* d_ws, size_t ws_size,
                              hipStream_t stream) {
  const float* x  = (const float*)d_in[0];
  const float* wq = (const float*)d_in[1];
  const float* wk = (const float*)d_in[2];
  const float* wv = (const float*)d_in[3];
  const float* wo = (const float*)d_in[4];
  float* out = (float*)d_out;
  char* ws = (char*)d_ws;

  short* x_bf  = (short*)(ws);                       // 8 MB
  short* WqkvT = (short*)(ws + ((size_t)8 << 20));   // 6 MB
  short* wo_bf = (short*)(ws + ((size_t)14 << 20));  // 2 MB
  short* Qb    = (short*)(ws + ((size_t)16 << 20));  // 8 MB
  short* Kb    = (short*)(ws + ((size_t)24 << 20));  // 8 MB
  short* Vt    = (short*)(ws + ((size_t)32 << 20));  // 8 MB (V^T)
  short* Ob    = (short*)(ws + ((size_t)40 << 20));  // 8 MB

  k_cast<<<4096, 256, 0, stream>>>(x, x_bf, 1048576);
  k_cast<<<1024, 256, 0, stream>>>(wo, wo_bf, 262144);
  k_pack<<<dim3(16, 16, 3), 256, 0, stream>>>(wq, wk, wv, WqkvT);
  k_gemm<0><<<dim3(24, 32), 256, 0, stream>>>(x_bf, WqkvT, Qb, Kb, Vt, nullptr, 4096, 3072, 1024);
  k_attn<<<dim3(32, 32), 128, 0, stream>>>(Qb, Kb, Vt, Ob);
  k_gemm<1><<<dim3(8, 32), 256, 0, stream>>>(Ob, wo_bf, nullptr, nullptr, nullptr, out, 4096, 1024, 1024);
}

// Round 8
// 141.067 us; speedup vs baseline: 1.0770x; 1.0321x over previous
//
#include <hip/hip_runtime.h>
#include <hip/hip_bf16.h>

typedef __attribute__((ext_vector_type(4)))  float f32x4;
typedef __attribute__((ext_vector_type(16))) float f32x16;
typedef __attribute__((ext_vector_type(8)))  short short8;
typedef __attribute__((ext_vector_type(4)))  short short4v;

__device__ __forceinline__ short f2bf(float f) {
  union { float f; unsigned u; } x; x.f = f;
  unsigned r = (x.u + 0x7FFFu + ((x.u >> 16) & 1u)) >> 16;
  return (short)r;
}
__device__ __forceinline__ unsigned cvtpk(float lo, float hi) {
  unsigned r;
  asm("v_cvt_pk_bf16_f32 %0, %1, %2" : "=v"(r) : "v"(lo), "v"(hi));
  return r;
}

// ---------------- cast f32 -> bf16, vectorized x4 ----------------
__global__ __launch_bounds__(256) void k_cast(const float* __restrict__ in,
                                              short* __restrict__ out, int n4) {
  int i = blockIdx.x * 256 + threadIdx.x;
  if (i >= n4) return;
  f32x4 v = ((const f32x4*)in)[i];
  short4v s;
  s[0] = f2bf(v[0]); s[1] = f2bf(v[1]); s[2] = f2bf(v[2]); s[3] = f2bf(v[3]);
  ((short4v*)out)[i] = s;
}

// ---------------- pack w_q/w_k/w_v -> WqkvT bf16 [3072][1024] ----------------
__global__ __launch_bounds__(256) void k_pack(const float* __restrict__ wq,
                                              const float* __restrict__ wk,
                                              const float* __restrict__ wv,
                                              short* __restrict__ WT) {
  int nt = blockIdx.x, et = blockIdx.y, sel = blockIdx.z;
  const float* w = sel == 0 ? wq : (sel == 1 ? wk : wv);
  __shared__ float tile[64][65];
  int tid = threadIdx.x;
  int cl = tid & 63, rw = tid >> 6;
#pragma unroll
  for (int j = 0; j < 16; ++j) {
    int el = j * 4 + rw;
    tile[el][cl] = w[(size_t)(et * 64 + el) * 1024 + nt * 64 + cl];
  }
  __syncthreads();
#pragma unroll
  for (int j = 0; j < 16; ++j) {
    int nl = j * 4 + rw;
    int n = sel * 1024 + nt * 64 + nl;
    WT[(size_t)n * 1024 + et * 64 + cl] = f2bf(tile[cl][nl]);
  }
}

// ---------------- GEMM C[M][N] = A[M][K] * B^T[N][K], bf16 in, f32 acc ----------------
// EPI==0: scatter Q(*0.125*log2e)/K -> [BH][2048][64], V -> V^T [BH][64][2048]; EPI==1: f32 out
template <int EPI>
__global__ __launch_bounds__(256) void k_gemm(const short* __restrict__ A,
                                              const short* __restrict__ B,
                                              short* __restrict__ Qo, short* __restrict__ Ko,
                                              short* __restrict__ Vo, float* __restrict__ out,
                                              int M, int N, int K) {
  __shared__ short As[128][40];
  __shared__ short Bs[128][40];
  int tid = threadIdx.x;
  int bm = blockIdx.y * 128, bn = blockIdx.x * 128;
  int wid = tid >> 6, lane = tid & 63;
  int wm = (wid >> 1) * 64, wn = (wid & 1) * 64;
  int lg = lane >> 4, lr = lane & 15;
  f32x4 acc[4][4] = {};

  int sr = tid >> 2, sc = tid & 3;
  const short* Ar0 = A + (size_t)(bm + sr) * K;
  const short* Ar1 = A + (size_t)(bm + sr + 64) * K;
  const short* Br0 = B + (size_t)(bn + sr) * K;
  const short* Br1 = B + (size_t)(bn + sr + 64) * K;

  short8 pa0 = *(const short8*)&Ar0[sc * 8];
  short8 pa1 = *(const short8*)&Ar1[sc * 8];
  short8 pb0 = *(const short8*)&Br0[sc * 8];
  short8 pb1 = *(const short8*)&Br1[sc * 8];

  int nk = K >> 5;
  for (int kt = 0; kt < nk; ++kt) {
    __syncthreads();
    *(short8*)&As[sr][sc * 8] = pa0;
    *(short8*)&As[sr + 64][sc * 8] = pa1;
    *(short8*)&Bs[sr][sc * 8] = pb0;
    *(short8*)&Bs[sr + 64][sc * 8] = pb1;
    if (kt + 1 < nk) {
      int ko = (kt + 1) * 32;
      pa0 = *(const short8*)&Ar0[ko + sc * 8];
      pa1 = *(const short8*)&Ar1[ko + sc * 8];
      pb0 = *(const short8*)&Br0[ko + sc * 8];
      pb1 = *(const short8*)&Br1[ko + sc * 8];
    }
    __syncthreads();
    short8 af[4], bf_[4];
#pragma unroll
    for (int mt = 0; mt < 4; ++mt)
      af[mt] = *(const short8*)&As[wm + mt * 16 + lr][lg * 8];
#pragma unroll
    for (int ntl = 0; ntl < 4; ++ntl)
      bf_[ntl] = *(const short8*)&Bs[wn + ntl * 16 + lr][lg * 8];
#pragma unroll
    for (int mt = 0; mt < 4; ++mt)
#pragma unroll
      for (int ntl = 0; ntl < 4; ++ntl)
        acc[mt][ntl] = __builtin_amdgcn_mfma_f32_16x16x32_bf16(af[mt], bf_[ntl], acc[mt][ntl], 0, 0, 0);
  }

#pragma unroll
  for (int mt = 0; mt < 4; ++mt)
#pragma unroll
    for (int ntl = 0; ntl < 4; ++ntl)
#pragma unroll
      for (int rr = 0; rr < 4; ++rr) {
        int m = bm + wm + mt * 16 + lg * 4 + rr;
        int n = bn + wn + ntl * 16 + lr;
        float val = acc[mt][ntl][rr];
        if (EPI == 0) {
          int b = m >> 11, s = m & 2047;
          int sel = n >> 10, hk = n & 1023;
          int h = hk >> 6, kd = hk & 63;
          // 0.125 * log2(e): logits in log2 domain -> exp2 in softmax
          if (sel == 0) Qo[((size_t)(b * 16 + h) * 2048 + s) * 64 + kd] = f2bf(val * 0.18033688011112042f);
          else if (sel == 1) Ko[((size_t)(b * 16 + h) * 2048 + s) * 64 + kd] = f2bf(val);
          else Vo[((size_t)(b * 16 + h) * 64 + kd) * 2048 + s] = f2bf(val);  // V^T
        } else {
          out[(size_t)m * 1024 + n] = val;
        }
      }
}

// ---------------- causal flash attention: LDS-shared tiles + LPT + setprio ----------------
// Q,K: [32][2048][64] bf16 (Q pre-scaled 1/8*log2e). VT: [32][64][2048]. O: [2][2048][1024] bf16.
// Block = 2 waves, wave w -> qw = 2g + w; g = 31 - blockIdx.y (LPT: longest blocks dispatch
// first, short blocks backfill the tail). Cross-lane ops via __shfl_xor (verified-passing).
__global__ __launch_bounds__(128, 2) void k_attn(const short* __restrict__ Q,
                                                 const short* __restrict__ K,
                                                 const short* __restrict__ VT,
                                                 short* __restrict__ O) {
  const int S = 2048;
  int bh = blockIdx.x;
  int g = 31 - blockIdx.y;  // LPT: longest first

  int tid = threadIdx.x;
  int wid = tid >> 6, lane = tid & 63;
  int hi = lane >> 5, ln = lane & 31;
  int qw = 2 * g + wid;
  int ntile = qw + 1;
  int tmax = 2 * g + 2;
  int q_g = qw * 32 + ln;

  __shared__ short Ks[2][32][64];
  __shared__ short Vs[2][64][32];

  const short* Qb = Q + (size_t)bh * S * 64;
  const short* Kb = K + (size_t)bh * S * 64;
  const short* Vb = VT + (size_t)bh * 64 * S;

  // Q fragments: B[k=d][col=q]
  short8 qf[4];
#pragma unroll
  for (int ds = 0; ds < 4; ++ds)
    qf[ds] = *(const short8*)&Qb[(size_t)q_g * 64 + ds * 16 + hi * 8];

  // staging thread mapping
  int kr = tid >> 2, kcb = tid & 3;          // K: row 0..31, chunks kcb, kcb+4
  int vd = tid >> 1, vcb = tid & 1;          // V: row d 0..63, chunks vcb, vcb+2
  const short* kgp = Kb + (size_t)kr * 64;
  const short* vgp = Vb + (size_t)vd * S;

  // prefetch tile 0
  short8 kreg0 = *(const short8*)&kgp[(size_t)0 + kcb * 8];
  short8 kreg1 = *(const short8*)&kgp[(size_t)0 + (kcb + 4) * 8];
  short8 vreg0 = *(const short8*)&vgp[(size_t)0 + vcb * 8];
  short8 vreg1 = *(const short8*)&vgp[(size_t)0 + (vcb + 2) * 8];

  f32x16 acoA = {}, acoB = {};
  float m = -1e30f, l = 0.f;

  for (int t = 0; t < tmax; ++t) {
    int buf = t & 1;
    // stage current tile (swizzled)
    *(short8*)&Ks[buf][kr][(kcb ^ (kr & 7)) * 8]       = kreg0;
    *(short8*)&Ks[buf][kr][((kcb + 4) ^ (kr & 7)) * 8] = kreg1;
    *(short8*)&Vs[buf][vd][(vcb ^ (vd & 3)) * 8]       = vreg0;
    *(short8*)&Vs[buf][vd][((vcb + 2) ^ (vd & 3)) * 8] = vreg1;
    // prefetch next tile (latency hides under compute)
    if (t + 1 < tmax) {
      size_t ko = (size_t)(t + 1) * 32 * 64;
      size_t vo = (size_t)(t + 1) * 32;
      kreg0 = *(const short8*)&kgp[ko + kcb * 8];
      kreg1 = *(const short8*)&kgp[ko + (kcb + 4) * 8];
      vreg0 = *(const short8*)&vgp[vo + vcb * 8];
      vreg1 = *(const short8*)&vgp[vo + (vcb + 2) * 8];
    }
    __syncthreads();

    if (t < ntile) {
      // K fragments from LDS: A[row=kv][k=d]
      short8 kc0 = *(const short8*)&Ks[buf][ln][((0 + hi) ^ (ln & 7)) * 8];
      short8 kc1 = *(const short8*)&Ks[buf][ln][((2 + hi) ^ (ln & 7)) * 8];
      short8 kc2 = *(const short8*)&Ks[buf][ln][((4 + hi) ^ (ln & 7)) * 8];
      short8 kc3 = *(const short8*)&Ks[buf][ln][((6 + hi) ^ (ln & 7)) * 8];
      // S[kv][q] = K Q^T (log2 domain)
      f32x16 sa = {};
      __builtin_amdgcn_s_setprio(1);
      sa = __builtin_amdgcn_mfma_f32_32x32x16_bf16(kc0, qf[0], sa, 0, 0, 0);
      sa = __builtin_amdgcn_mfma_f32_32x32x16_bf16(kc1, qf[1], sa, 0, 0, 0);
      sa = __builtin_amdgcn_mfma_f32_32x32x16_bf16(kc2, qf[2], sa, 0, 0, 0);
      sa = __builtin_amdgcn_mfma_f32_32x32x16_bf16(kc3, qf[3], sa, 0, 0, 0);
      __builtin_amdgcn_s_setprio(0);

      if (t == qw) {  // diagonal tile: causal mask
#pragma unroll
        for (int r = 0; r < 16; ++r) {
          int kv_g = t * 32 + (r & 3) + 8 * (r >> 2) + 4 * hi;
          if (kv_g > q_g) sa[r] = -1e30f;
        }
      }

      // V^T fragments from LDS: A[row=d][k=kv]
      short8 v00 = *(const short8*)&Vs[buf][ln][((0 + hi) ^ (ln & 3)) * 8];
      short8 v01 = *(const short8*)&Vs[buf][ln][((2 + hi) ^ (ln & 3)) * 8];
      short8 v10 = *(const short8*)&Vs[buf][32 + ln][((0 + hi) ^ (ln & 3)) * 8];
      short8 v11 = *(const short8*)&Vs[buf][32 + ln][((2 + hi) ^ (ln & 3)) * 8];

      // row max: in-register tree + one cross-lane shfl
      float x0 = fmaxf(sa[0], sa[1]),  x1 = fmaxf(sa[2], sa[3]);
      float x2 = fmaxf(sa[4], sa[5]),  x3 = fmaxf(sa[6], sa[7]);
      float x4 = fmaxf(sa[8], sa[9]),  x5 = fmaxf(sa[10], sa[11]);
      float x6 = fmaxf(sa[12], sa[13]), x7 = fmaxf(sa[14], sa[15]);
      x0 = fmaxf(x0, x1); x2 = fmaxf(x2, x3); x4 = fmaxf(x4, x5); x6 = fmaxf(x6, x7);
      x0 = fmaxf(x0, x2); x4 = fmaxf(x4, x6);
      float mx = fmaxf(x0, x4);
      mx = fmaxf(mx, __shfl_xor(mx, 32));

      float mnew = fmaxf(m, mx);
      float p[16];
#pragma unroll
      for (int r = 0; r < 16; ++r) p[r] = exp2f(sa[r] - mnew);
      float s0 = (p[0] + p[1]) + (p[2] + p[3]);
      float s1 = (p[4] + p[5]) + (p[6] + p[7]);
      float s2 = (p[8] + p[9]) + (p[10] + p[11]);
      float s3 = (p[12] + p[13]) + (p[14] + p[15]);
      float rsum = (s0 + s1) + (s2 + s3);
      rsum += __shfl_xor(rsum, 32);

      if (__all(mx <= m)) {  // exact skip: alpha == 1
        l += rsum;
      } else {
        float alpha = exp2f(m - mnew);
        m = mnew;
        l = l * alpha + rsum;
        acoA *= alpha;
        acoB *= alpha;
      }

      // assemble P^T fragments (B[k=kv][col=q]) via cvt_pk + lane^32 exchange
#pragma unroll
      for (int s = 0; s < 2; ++s) {
        unsigned c0 = cvtpk(p[8 * s + 0], p[8 * s + 1]);
        unsigned c1 = cvtpk(p[8 * s + 2], p[8 * s + 3]);
        unsigned c2 = cvtpk(p[8 * s + 4], p[8 * s + 5]);
        unsigned c3 = cvtpk(p[8 * s + 6], p[8 * s + 7]);
        unsigned pc0 = (unsigned)__shfl_xor((int)c0, 32);
        unsigned pc1 = (unsigned)__shfl_xor((int)c1, 32);
        unsigned pc2 = (unsigned)__shfl_xor((int)c2, 32);
        unsigned pc3 = (unsigned)__shfl_xor((int)c3, 32);
        union { unsigned u[4]; short8 v; } pb;
        pb.u[0] = hi ? pc2 : c0;
        pb.u[1] = hi ? pc3 : c1;
        pb.u[2] = hi ? c2 : pc0;
        pb.u[3] = hi ? c3 : pc1;
        __builtin_amdgcn_s_setprio(1);
        if (s == 0) {
          acoA = __builtin_amdgcn_mfma_f32_32x32x16_bf16(v00, pb.v, acoA, 0, 0, 0);
          acoB = __builtin_amdgcn_mfma_f32_32x32x16_bf16(v10, pb.v, acoB, 0, 0, 0);
        } else {
          acoA = __builtin_amdgcn_mfma_f32_32x32x16_bf16(v01, pb.v, acoA, 0, 0, 0);
          acoB = __builtin_amdgcn_mfma_f32_32x32x16_bf16(v11, pb.v, acoB, 0, 0, 0);
        }
        __builtin_amdgcn_s_setprio(0);
      }
    }
  }

  // normalized output: O[d][q] acc, lane-local q
  float rl = 1.f / l;
  int b = bh >> 4, h = bh & 15;
  size_t obase = ((size_t)b * 2048 + q_g) * 1024 + h * 64;
#pragma unroll
  for (int g4 = 0; g4 < 4; ++g4) {
    int d0 = 8 * g4 + 4 * hi;
    *(unsigned*)&O[obase + d0]          = cvtpk(acoA[4 * g4] * rl, acoA[4 * g4 + 1] * rl);
    *(unsigned*)&O[obase + d0 + 2]      = cvtpk(acoA[4 * g4 + 2] * rl, acoA[4 * g4 + 3] * rl);
    *(unsigned*)&O[obase + 32 + d0]     = cvtpk(acoB[4 * g4] * rl, acoB[4 * g4 + 1] * rl);
    *(unsigned*)&O[obase + 32 + d0 + 2] = cvtpk(acoB[4 * g4 + 2] * rl, acoB[4 * g4 + 3] * rl);
  }
}

extern "C" void kernel_launch(void* const* d_in, const int* in_sizes, int n_in,
                              void* d_out, int out_size, void* d_ws, size_t ws_size,
                              hipStream_t stream) {
  const float* x  = (const float*)d_in[0];
  const float* wq = (const float*)d_in[1];
  const float* wk = (const float*)d_in[2];
  const float* wv = (const float*)d_in[3];
  const float* wo = (const float*)d_in[4];
  float* out = (float*)d_out;
  char* ws = (char*)d_ws;

  short* x_bf  = (short*)(ws);                       // 8 MB
  short* WqkvT = (short*)(ws + ((size_t)8 << 20));   // 6 MB
  short* wo_bf = (short*)(ws + ((size_t)14 << 20));  // 2 MB
  short* Qb    = (short*)(ws + ((size_t)16 << 20));  // 8 MB
  short* Kb    = (short*)(ws + ((size_t)24 << 20));  // 8 MB
  short* Vt    = (short*)(ws + ((size_t)32 << 20));  // 8 MB (V^T)
  short* Ob    = (short*)(ws + ((size_t)40 << 20));  // 8 MB

  k_cast<<<4096, 256, 0, stream>>>(x, x_bf, 1048576);
  k_cast<<<1024, 256, 0, stream>>>(wo, wo_bf, 262144);
  k_pack<<<dim3(16, 16, 3), 256, 0, stream>>>(wq, wk, wv, WqkvT);
  k_gemm<0><<<dim3(24, 32), 256, 0, stream>>>(x_bf, WqkvT, Qb, Kb, Vt, nullptr, 4096, 3072, 1024);
  k_attn<<<dim3(32, 32), 128, 0, stream>>>(Qb, Kb, Vt, Ob);
  k_gemm<1><<<dim3(8, 32), 256, 0, stream>>>(Ob, wo_bf, nullptr, nullptr, nullptr, out, 4096, 1024, 1024);
}